// Round 1
// baseline (296.185 us; speedup 1.0000x reference)
//
#include <hip/hip_runtime.h>
#include <hip/hip_bf16.h>
#include <stdint.h>

#define NB   8
#define NSEQ 4096
#define DIN  128
#define DK   64
#define DVV  128

typedef __bf16 bf16x8 __attribute__((ext_vector_type(8)));
typedef float f32x4 __attribute__((ext_vector_type(4)));
typedef unsigned short u16;
typedef unsigned int u32;

__device__ __forceinline__ u16 f2bf(float f) {
  union { float f; u32 u; } v; v.f = f;
  u32 r = v.u + 0x7FFFu + ((v.u >> 16) & 1u);  // RNE
  return (u16)(r >> 16);
}

// ---------------- projection: Q,K  (out layout [b][n][64] bf16) ----------------
// Q is pre-scaled by log2(e)/8 so attention can use exp2 directly.
__global__ __launch_bounds__(256) void proj_qk(
    const float* __restrict__ x, const float* __restrict__ Wq,
    const float* __restrict__ Wk, u16* __restrict__ Qb, u16* __restrict__ Kb) {
  const int w = threadIdx.x >> 6, l = threadIdx.x & 63;
  const int gw = blockIdx.x * 4 + w;        // 8192 waves: b(8) x mat(2) x ng(512)
  const int b = gw >> 10;
  const int rem = gw & 1023;
  const int mat = rem >> 9;
  const int n0 = (rem & 511) << 3;
  const float* W = mat ? Wk : Wq;
  const float scale = mat ? 1.0f : 0.180336880111120429f;  // log2e/8
  u16* out = mat ? Kb : Qb;
  const float* wrow = W + l * DIN;          // lane = output channel kk
  const float* xb = x + (size_t)b * DIN * NSEQ + n0;
  float acc[8] = {0.f,0.f,0.f,0.f,0.f,0.f,0.f,0.f};
  #pragma unroll 4
  for (int d = 0; d < DIN; ++d) {
    const float wv = wrow[d];
    const float* xr = xb + (size_t)d * NSEQ;   // wave-uniform address
    const float4 a = *(const float4*)(xr);
    const float4 c = *(const float4*)(xr + 4);
    acc[0] += wv * a.x; acc[1] += wv * a.y; acc[2] += wv * a.z; acc[3] += wv * a.w;
    acc[4] += wv * c.x; acc[5] += wv * c.y; acc[6] += wv * c.z; acc[7] += wv * c.w;
  }
  u16* o = out + ((size_t)(b * NSEQ + n0) * DK + l);
  #pragma unroll
  for (int j = 0; j < 8; ++j) o[j * DK] = f2bf(acc[j] * scale);
}

// ---------------- projection: V^T  (out layout [b][dv][n] bf16) ----------------
__global__ __launch_bounds__(256) void proj_v(
    const float* __restrict__ x, const float* __restrict__ Wv, u16* __restrict__ Vtb) {
  const int w = threadIdx.x >> 6, l = threadIdx.x & 63;
  const int gw = blockIdx.x * 4 + w;        // 8192 waves: b(8) x dg(16) x ng(64)
  const int b = gw >> 10;
  const int rem = gw & 1023;
  const int dg = rem >> 6;
  const int n = ((rem & 63) << 6) + l;      // lane = n (coalesced)
  const int dv0 = dg << 3;
  const float* xb = x + (size_t)b * DIN * NSEQ + n;
  const float* wb = Wv + dv0 * DIN;
  float acc[8] = {0.f,0.f,0.f,0.f,0.f,0.f,0.f,0.f};
  #pragma unroll 4
  for (int d = 0; d < DIN; ++d) {
    const float xv = xb[(size_t)d * NSEQ];
    #pragma unroll
    for (int j = 0; j < 8; ++j) acc[j] += wb[j * DIN + d] * xv;  // uniform W loads
  }
  #pragma unroll
  for (int j = 0; j < 8; ++j)
    Vtb[((size_t)b * DVV + dv0 + j) * NSEQ + n] = f2bf(acc[j]);
}

// ---------------- fused flash attention + transpose + residual ----------------
// Block: 256 threads (4 waves), QB=64 (wave w owns q-rows n0+16w..+15), KVBLK=64.
// LDS: 2 x (K 8KB + Vt 16KB) double buffer + 4 x 2KB per-wave P = 56KB.
// All K/Vt/P tiles XOR-swizzled per 16B chunk: chunk' = chunk ^ (row & 7).
__global__ __launch_bounds__(256, 2) void attn(
    const u16* __restrict__ Qb, const u16* __restrict__ Kb,
    const u16* __restrict__ Vtb, const float* __restrict__ x,
    float* __restrict__ out) {
  __shared__ alignas(16) char lds[57344];
  const int tid = threadIdx.x;
  const int w = tid >> 6, l = tid & 63;
  const int lg = l >> 4, li = l & 15;
  const int b = blockIdx.x >> 6;
  const int n0 = (blockIdx.x & 63) << 6;

  // Q A-fragments (16x32 each): lane holds row li, d-chunk lg*8..+7 (+32 for qf1)
  bf16x8 qf0, qf1;
  {
    const u16* qp = Qb + ((size_t)(b * NSEQ + n0 + w * 16 + li) * DK + lg * 8);
    qf0 = *(const bf16x8*)qp;
    qf1 = *(const bf16x8*)(qp + 32);
  }

  const f32x4 fzero = {0.f, 0.f, 0.f, 0.f};
  f32x4 oacc[8];
  #pragma unroll
  for (int dt = 0; dt < 8; ++dt) oacc[dt] = fzero;
  float mrow[4] = {-1e30f, -1e30f, -1e30f, -1e30f};
  float lrow[4] = {0.f, 0.f, 0.f, 0.f};

  // staging: 6 slots of 16B per lane per tile (K:2, V:4); swizzle folded into src
  const u16* ksrc[2];
  const u16* vsrc[4];
  int koff[2], voff[4];
  #pragma unroll
  for (int q = 0; q < 2; ++q) {
    const int s = (w * 2 + q) * 64 + l;        // K slot 0..511
    const int row = s >> 3, ch = (s & 7) ^ (row & 7);
    ksrc[q] = Kb + ((size_t)(b * NSEQ + row) * DK + ch * 8);
    koff[q] = s * 16;
  }
  #pragma unroll
  for (int q = 0; q < 4; ++q) {
    const int s = (w * 4 + q) * 64 + l;        // V slot 0..1023
    const int row = s >> 3, ch = (s & 7) ^ (row & 7);
    vsrc[q] = Vtb + ((size_t)(b * DVV + row) * NSEQ + ch * 8);
    voff[q] = s * 16;
  }
  char* const pbuf = lds + 49152 + w * 2048;

  uint4 stg[6];
#define LOADT(T) do {                                                         \
    _Pragma("unroll") for (int q = 0; q < 2; ++q)                             \
      stg[q] = *(const uint4*)(ksrc[q] + (size_t)(T) * 4096);                 \
    _Pragma("unroll") for (int q = 0; q < 4; ++q)                             \
      stg[2 + q] = *(const uint4*)(vsrc[q] + (size_t)(T) * 64);               \
  } while (0)
#define WRITET(BUF) do {                                                      \
    char* kb_ = lds + (BUF) * 24576;                                          \
    char* vb_ = kb_ + 8192;                                                   \
    _Pragma("unroll") for (int q = 0; q < 2; ++q)                             \
      *(uint4*)(kb_ + koff[q]) = stg[q];                                      \
    _Pragma("unroll") for (int q = 0; q < 4; ++q)                             \
      *(uint4*)(vb_ + voff[q]) = stg[2 + q];                                  \
  } while (0)

  LOADT(0);
  WRITET(0);

  for (int t = 0; t < 64; ++t) {
    const int cur = t & 1;
    __syncthreads();                 // stage(t) visible to all; buf cur ready
    if (t < 63) LOADT(t + 1);        // issue next-tile loads early (hide HBM)

    const char* kb = lds + cur * 24576;
    const char* vb = kb + 8192;

    // ---- S = Q K^T (rows q, cols j) ----
    f32x4 sacc[4];
    #pragma unroll
    for (int jt = 0; jt < 4; ++jt) {
      sacc[jt] = fzero;
      const int row = jt * 16 + li;                  // K row (= output col j)
      const int rx = row & 7;
      bf16x8 kf0 = *(const bf16x8*)(kb + row * 128 + ((lg ^ rx) * 16));
      bf16x8 kf1 = *(const bf16x8*)(kb + row * 128 + (((4 + lg) ^ rx) * 16));
      sacc[jt] = __builtin_amdgcn_mfma_f32_16x16x32_bf16(qf0, kf0, sacc[jt], 0, 0, 0);
      sacc[jt] = __builtin_amdgcn_mfma_f32_16x16x32_bf16(qf1, kf1, sacc[jt], 0, 0, 0);
    }

    // ---- online softmax (exp2 domain; Q carried log2e/8) ----
    #pragma unroll
    for (int r = 0; r < 4; ++r) {
      float mx = fmaxf(fmaxf(sacc[0][r], sacc[1][r]), fmaxf(sacc[2][r], sacc[3][r]));
      #pragma unroll
      for (int d = 1; d < 16; d <<= 1) mx = fmaxf(mx, __shfl_xor(mx, d, 64));
      const float mn = fmaxf(mrow[r], mx);
      const float corr = __builtin_amdgcn_exp2f(mrow[r] - mn);
      mrow[r] = mn;
      float ps = 0.f;
      #pragma unroll
      for (int jt = 0; jt < 4; ++jt) {
        const float p = __builtin_amdgcn_exp2f(sacc[jt][r] - mn);
        sacc[jt][r] = p;
        ps += p;
      }
      #pragma unroll
      for (int d = 1; d < 16; d <<= 1) ps += __shfl_xor(ps, d, 64);
      lrow[r] = lrow[r] * corr + ps;
      #pragma unroll
      for (int dt = 0; dt < 8; ++dt) oacc[dt][r] *= corr;
    }

    // ---- P -> per-wave LDS (bf16, swizzled) ----
    #pragma unroll
    for (int jt = 0; jt < 4; ++jt) {
      #pragma unroll
      for (int r = 0; r < 4; ++r) {
        const int row = lg * 4 + r;
        const int col = jt * 16 + li;
        const int ch = (col >> 3) ^ (row & 7);
        *(u16*)(pbuf + row * 128 + ch * 16 + (col & 7) * 2) = f2bf(sacc[jt][r]);
      }
    }

    // ---- P A-fragments back ----
    const int prx = li & 7;
    bf16x8 pf0 = *(const bf16x8*)(pbuf + li * 128 + ((lg ^ prx) * 16));
    bf16x8 pf1 = *(const bf16x8*)(pbuf + li * 128 + (((4 + lg) ^ prx) * 16));

    // ---- O += P V ----
    #pragma unroll
    for (int dt = 0; dt < 8; ++dt) {
      const int dv = dt * 16 + li;                   // Vt row (= output col dv)
      const int dx = dv & 7;
      bf16x8 vf0 = *(const bf16x8*)(vb + dv * 128 + ((lg ^ dx) * 16));
      bf16x8 vf1 = *(const bf16x8*)(vb + dv * 128 + (((4 + lg) ^ dx) * 16));
      oacc[dt] = __builtin_amdgcn_mfma_f32_16x16x32_bf16(pf0, vf0, oacc[dt], 0, 0, 0);
      oacc[dt] = __builtin_amdgcn_mfma_f32_16x16x32_bf16(pf1, vf1, oacc[dt], 0, 0, 0);
    }

    if (t < 63) WRITET(cur ^ 1);     // ds_write the prefetched tile (after compute)
  }

  // ---- epilogue: O/l, transpose via LDS, add residual x, coalesced store ----
  __syncthreads();                   // safe to reuse K/V LDS region
  float rl[4];
  #pragma unroll
  for (int r = 0; r < 4; ++r) rl[r] = 1.0f / lrow[r];
  float* ol = (float*)(lds + w * 8704);              // [128 dv][17] padded
  #pragma unroll
  for (int dt = 0; dt < 8; ++dt) {
    #pragma unroll
    for (int r = 0; r < 4; ++r)
      ol[(dt * 16 + li) * 17 + lg * 4 + r] = oacc[dt][r] * rl[r];
  }
  for (int it = 0; it < 32; ++it) {
    const int dv = it * 4 + lg;
    const size_t idx = ((size_t)b * DVV + dv) * NSEQ + (n0 + w * 16 + li);
    out[idx] = ol[dv * 17 + li] + x[idx];
  }
#undef LOADT
#undef WRITET
}

extern "C" void kernel_launch(void* const* d_in, const int* in_sizes, int n_in,
                              void* d_out, int out_size, void* d_ws, size_t ws_size,
                              hipStream_t stream) {
  const float* x  = (const float*)d_in[0];
  const float* Wq = (const float*)d_in[1];
  const float* Wk = (const float*)d_in[2];
  const float* Wv = (const float*)d_in[3];
  float* out = (float*)d_out;

  u16* qws = (u16*)d_ws;                                   // [8][4096][64]
  u16* kws = qws + (size_t)NB * NSEQ * DK;                 // [8][4096][64]
  u16* vws = kws + (size_t)NB * NSEQ * DK;                 // [8][128][4096]

  proj_qk<<<2048, 256, 0, stream>>>(x, Wq, Wk, qws, kws);
  proj_v <<<2048, 256, 0, stream>>>(x, Wv, vws);
  attn   <<<512,  256, 0, stream>>>(qws, kws, vws, x, out);
}

// Round 2
// 129.494 us; speedup vs baseline: 2.2872x; 2.2872x over previous
//
#include <hip/hip_runtime.h>
#include <hip/hip_bf16.h>
#include <stdint.h>

#define NB   8
#define NSEQ 4096
#define DIN  128
#define DK   64
#define DVV  128

typedef __bf16 bf16x8 __attribute__((ext_vector_type(8)));
typedef float f32x4 __attribute__((ext_vector_type(4)));
typedef unsigned int u32x4v __attribute__((ext_vector_type(4)));
typedef unsigned short u16;
typedef unsigned int u32;

__device__ __forceinline__ u16 f2bf(float f) {
  union { float f; u32 u; } v; v.f = f;
  u32 r = v.u + 0x7FFFu + ((v.u >> 16) & 1u);  // RNE
  return (u16)(r >> 16);
}

__device__ __forceinline__ u32 cvt_pk_bf16(float lo, float hi) {
  u32 r;
  asm("v_cvt_pk_bf16_f32 %0, %1, %2" : "=v"(r) : "v"(lo), "v"(hi));
  return r;
}

// ---------------- unified projection kernel ----------------
// block = 64 (one wave) so blockIdx-derived W pointers are SGPR-uniform.
// 8192 blocks: b(8) x cg(16) x ng(64). cg 0-3: Q, 4-7: K, 8-15: V.
// lane = n (coalesced x reads). Q pre-scaled by log2e/8.
__global__ __launch_bounds__(64) void proj(
    const float* __restrict__ x, const float* __restrict__ Wq,
    const float* __restrict__ Wk, const float* __restrict__ Wv,
    u16* __restrict__ Qb, u16* __restrict__ Kb, u16* __restrict__ Vtb) {
  const int l = threadIdx.x;
  const int gw = blockIdx.x;
  const int b = gw >> 10;
  const int cg = (gw >> 6) & 15;
  const int n = ((gw & 63) << 6) + l;

  const float* wb;
  float scale = 1.0f;
  if (cg < 4)      { wb = Wq + cg * 16 * DIN; scale = 0.180336880111120429f; }
  else if (cg < 8) { wb = Wk + (cg - 4) * 16 * DIN; }
  else             { wb = Wv + (cg - 8) * 16 * DIN; }

  const float* xb = x + (size_t)b * DIN * NSEQ + n;
  float acc[16];
  #pragma unroll
  for (int j = 0; j < 16; ++j) acc[j] = 0.f;

  #pragma unroll 4
  for (int d = 0; d < DIN; ++d) {
    const float xv = xb[(size_t)d * NSEQ];
    #pragma unroll
    for (int j = 0; j < 16; ++j) acc[j] += wb[j * DIN + d] * xv;
  }

  if (cg < 8) {
    u16* ob = (cg < 4 ? Qb : Kb) + ((size_t)b * NSEQ + n) * DK + (cg & 3) * 16;
    u32 pk[8];
    #pragma unroll
    for (int i = 0; i < 8; ++i)
      pk[i] = cvt_pk_bf16(acc[2 * i] * scale, acc[2 * i + 1] * scale);
    *(uint4*)(ob)     = *(uint4*)(&pk[0]);
    *(uint4*)(ob + 8) = *(uint4*)(&pk[4]);
  } else {
    const int dv0 = (cg - 8) * 16;
    #pragma unroll
    for (int j = 0; j < 16; ++j)
      Vtb[((size_t)b * DVV + dv0 + j) * NSEQ + n] = f2bf(acc[j]);
  }
}

// ---------------- fused flash attention (swapped-operand, in-register softmax) ----
// Block: 256 threads (4 waves), each wave owns 16 q rows. KVBLK = 64.
// S^T = mfma(K_frag, Q_frag): lane holds col q=li, rows kv (16 values).
// K rows per QK tile jt are PERMUTED (T_jt[m] = 32(jt>>1)+8(m>>2)+4(jt&1)+(m&3),
// folded into staging source pointers) so each lane's 16 P values form its PV
// B-fragment directly: pf[h] = [p[2h][0..3], p[2h+1][0..3]]. No P LDS round-trip.
// PV swapped too: O^T = mfma(V_frag, P_frag) -> softmax stats stay lane-local.
// LDS: 2 x (K 8KB + Vt 16KB) double buffer = 48KB, XOR chunk swizzle.
__global__ __launch_bounds__(256, 2) void attn(
    const u16* __restrict__ Qb, const u16* __restrict__ Kb,
    const u16* __restrict__ Vtb, const float* __restrict__ x,
    float* __restrict__ out) {
  __shared__ alignas(16) char lds[49152];
  const int tid = threadIdx.x;
  const int w = tid >> 6, l = tid & 63;
  const int lg = l >> 4, li = l & 15;
  const int b = blockIdx.x >> 6;
  const int n0 = (blockIdx.x & 63) << 6;
  const int q = n0 + w * 16 + li;

  // Q B-fragments: lane holds col q=li, d-chunk lg*8 (+32 for h=1)
  bf16x8 qf0, qf1;
  {
    const u16* qp = Qb + ((size_t)(b * NSEQ + q) * DK + lg * 8);
    qf0 = *(const bf16x8*)qp;
    qf1 = *(const bf16x8*)(qp + 32);
  }

  const f32x4 fzero = {0.f, 0.f, 0.f, 0.f};
  f32x4 oacc[8];
  #pragma unroll
  for (int dt = 0; dt < 8; ++dt) oacc[dt] = fzero;
  float mrow = -1e30f, lrow = 0.f;

  // staging: 6 slots of 16B per lane per tile (K:2, V:4)
  // K is staged with permuted rows + XOR chunk swizzle folded into the source.
  const u16* ksrc[2];
  const u16* vsrc[4];
  int koff[2], voff[4];
  #pragma unroll
  for (int s2 = 0; s2 < 2; ++s2) {
    const int s = (w * 2 + s2) * 64 + l;      // K slot 0..511
    const int rho = s >> 3, c = s & 7;
    const int jt = rho >> 4, m = rho & 15;
    const int kvrow = 32 * (jt >> 1) + 8 * (m >> 2) + 4 * (jt & 1) + (m & 3);
    ksrc[s2] = Kb + ((size_t)(b * NSEQ + kvrow) * DK + (c ^ (rho & 7)) * 8);
    koff[s2] = s * 16;
  }
  #pragma unroll
  for (int s2 = 0; s2 < 4; ++s2) {
    const int s = (w * 4 + s2) * 64 + l;      // V slot 0..1023
    const int rho = s >> 3, c = s & 7;
    vsrc[s2] = Vtb + ((size_t)(b * DVV + rho) * NSEQ + (c ^ (rho & 7)) * 8);
    voff[s2] = s * 16;
  }

  uint4 stg[6];
#define LOADT(T) do {                                                         \
    _Pragma("unroll") for (int s2 = 0; s2 < 2; ++s2)                          \
      stg[s2] = *(const uint4*)(ksrc[s2] + (size_t)(T) * 4096);               \
    _Pragma("unroll") for (int s2 = 0; s2 < 4; ++s2)                          \
      stg[2 + s2] = *(const uint4*)(vsrc[s2] + (size_t)(T) * 64);             \
  } while (0)
#define WRITET(BUF) do {                                                      \
    char* kb_ = lds + (BUF) * 24576;                                          \
    char* vb_ = kb_ + 8192;                                                   \
    _Pragma("unroll") for (int s2 = 0; s2 < 2; ++s2)                          \
      *(uint4*)(kb_ + koff[s2]) = stg[s2];                                    \
    _Pragma("unroll") for (int s2 = 0; s2 < 4; ++s2)                          \
      *(uint4*)(vb_ + voff[s2]) = stg[2 + s2];                                \
  } while (0)

  LOADT(0);
  WRITET(0);

  for (int t = 0; t < 64; ++t) {
    const int cur = t & 1;
    __syncthreads();                 // buf cur ready for all waves
    if (t < 63) LOADT(t + 1);        // issue next-tile loads early

    const char* kb = lds + cur * 24576;
    const char* vb = kb + 8192;

    // ---- S^T = K Q^T (rows kv-permuted, cols q) ----
    f32x4 s4[4];
    #pragma unroll
    for (int jt = 0; jt < 4; ++jt) {
      s4[jt] = fzero;
      const int row = jt * 16 + li;
      const int sw = row & 7;
      bf16x8 kf0 = *(const bf16x8*)(kb + row * 128 + ((lg ^ sw) * 16));
      bf16x8 kf1 = *(const bf16x8*)(kb + row * 128 + (((lg + 4) ^ sw) * 16));
      s4[jt] = __builtin_amdgcn_mfma_f32_16x16x32_bf16(kf0, qf0, s4[jt], 0, 0, 0);
      s4[jt] = __builtin_amdgcn_mfma_f32_16x16x32_bf16(kf1, qf1, s4[jt], 0, 0, 0);
    }

    // ---- in-lane online softmax (exp2 domain; Q carried log2e/8) ----
    float mx = s4[0][0];
    #pragma unroll
    for (int jt = 0; jt < 4; ++jt)
      #pragma unroll
      for (int r = 0; r < 4; ++r) mx = fmaxf(mx, s4[jt][r]);
    mx = fmaxf(mx, __shfl_xor(mx, 16, 64));
    mx = fmaxf(mx, __shfl_xor(mx, 32, 64));
    if (__any(mx > mrow)) {
      const float mn = fmaxf(mrow, mx);
      const float corr = __builtin_amdgcn_exp2f(mrow - mn);
      mrow = mn;
      lrow *= corr;
      #pragma unroll
      for (int dt = 0; dt < 8; ++dt) oacc[dt] *= corr;
    }
    float ps = 0.f;
    #pragma unroll
    for (int jt = 0; jt < 4; ++jt)
      #pragma unroll
      for (int r = 0; r < 4; ++r) {
        const float p = __builtin_amdgcn_exp2f(s4[jt][r] - mrow);
        s4[jt][r] = p;
        ps += p;
      }
    ps += __shfl_xor(ps, 16, 64);
    ps += __shfl_xor(ps, 32, 64);
    lrow += ps;

    // ---- P -> PV B-fragments, pure in-lane packing (permutation magic) ----
    u32x4v pk0, pk1;
    pk0[0] = cvt_pk_bf16(s4[0][0], s4[0][1]);
    pk0[1] = cvt_pk_bf16(s4[0][2], s4[0][3]);
    pk0[2] = cvt_pk_bf16(s4[1][0], s4[1][1]);
    pk0[3] = cvt_pk_bf16(s4[1][2], s4[1][3]);
    pk1[0] = cvt_pk_bf16(s4[2][0], s4[2][1]);
    pk1[1] = cvt_pk_bf16(s4[2][2], s4[2][3]);
    pk1[2] = cvt_pk_bf16(s4[3][0], s4[3][1]);
    pk1[3] = cvt_pk_bf16(s4[3][2], s4[3][3]);
    const bf16x8 pf0 = __builtin_bit_cast(bf16x8, pk0);
    const bf16x8 pf1 = __builtin_bit_cast(bf16x8, pk1);

    // ---- O^T += V^T P ----
    #pragma unroll
    for (int dt = 0; dt < 8; ++dt) {
      const int row = dt * 16 + li;
      const int sw = row & 7;
      bf16x8 vf0 = *(const bf16x8*)(vb + row * 128 + ((lg ^ sw) * 16));
      bf16x8 vf1 = *(const bf16x8*)(vb + row * 128 + (((lg + 4) ^ sw) * 16));
      oacc[dt] = __builtin_amdgcn_mfma_f32_16x16x32_bf16(vf0, pf0, oacc[dt], 0, 0, 0);
      oacc[dt] = __builtin_amdgcn_mfma_f32_16x16x32_bf16(vf1, pf1, oacc[dt], 0, 0, 0);
    }

    if (t < 63) WRITET(cur ^ 1);     // ds_write prefetched tile after compute
  }

  // ---- epilogue: O/l + residual, direct store (lane q=li is contiguous n) ----
  const float rl = 1.0f / lrow;
  #pragma unroll
  for (int dt = 0; dt < 8; ++dt) {
    #pragma unroll
    for (int r = 0; r < 4; ++r) {
      const int dv = dt * 16 + 4 * lg + r;
      const size_t idx = ((size_t)b * DVV + dv) * NSEQ + q;
      out[idx] = oacc[dt][r] * rl + x[idx];
    }
  }
#undef LOADT
#undef WRITET
}

extern "C" void kernel_launch(void* const* d_in, const int* in_sizes, int n_in,
                              void* d_out, int out_size, void* d_ws, size_t ws_size,
                              hipStream_t stream) {
  const float* x  = (const float*)d_in[0];
  const float* Wq = (const float*)d_in[1];
  const float* Wk = (const float*)d_in[2];
  const float* Wv = (const float*)d_in[3];
  float* out = (float*)d_out;

  u16* qws = (u16*)d_ws;                                   // [8][4096][64]
  u16* kws = qws + (size_t)NB * NSEQ * DK;                 // [8][4096][64]
  u16* vws = kws + (size_t)NB * NSEQ * DK;                 // [8][128][4096]

  proj<<<8192, 64, 0, stream>>>(x, Wq, Wk, Wv, qws, kws, vws);
  attn<<<512, 256, 0, stream>>>(qws, kws, vws, x, out);
}